// Round 14
// baseline (180.744 us; speedup 1.0000x reference)
//
#include <hip/hip_runtime.h>

typedef unsigned short u16;
typedef __attribute__((ext_vector_type(8))) short short8;
typedef __attribute__((ext_vector_type(4))) short short4v;
typedef __attribute__((ext_vector_type(2))) int int2v;
typedef __attribute__((ext_vector_type(4))) float f32x4;

#define DIM   768
#define HEADS 12
#define HD    64
#define BATCH 8
#define SEQ   1024
#define MTOK  (BATCH*SEQ)   /* 8192 */
#define NQKV  (3*DIM)       /* 2304 */
#define KP    72            /* attn P-region row stride (144B = 9*16B, b128-aligned) */
#define EPAD  66            /* gemm epilogue stage stride */
#define PSZ   ((size_t)BATCH*HEADS*SEQ*HD)   /* one of q/k/v */
#define SCQ   0.1803368801f /* hd^-0.5 * log2(e), folded into stored q */

__device__ __forceinline__ u16 f2bf(float f) {
  unsigned x = __float_as_uint(f);
  x += 0x7fffu + ((x >> 16) & 1u);      // RNE
  return (u16)(x >> 16);
}

__device__ __forceinline__ void gload16(const u16* g, u16* l) {
  __builtin_amdgcn_global_load_lds(
      (const __attribute__((address_space(1))) unsigned int*)g,
      (__attribute__((address_space(3))) unsigned int*)l, 16, 0, 0);
}

// ---------------- fused conversions: x->bf16, Wqkv^T, Wproj^T ----------------
#define XBLK 6144            /* MTOK*DIM/4/256 */
#define QTBLK 1728           /* (NQKV/32)*(DIM/32) */
__global__ void cvt_all_k(const float* __restrict__ x,
                          const float* __restrict__ Wqkv,
                          const float* __restrict__ Wproj,
                          u16* __restrict__ xb, u16* __restrict__ wqkvt,
                          u16* __restrict__ wprojt) {
  __shared__ u16 tile[32][33];
  const int blk = blockIdx.x;
  if (blk < XBLK) {
    const int i = blk * 256 + threadIdx.x;
    float4 f = ((const float4*)x)[i];
    short4v o;
    o.x = (short)f2bf(f.x); o.y = (short)f2bf(f.y);
    o.z = (short)f2bf(f.z); o.w = (short)f2bf(f.w);
    ((short4v*)xb)[i] = o;
    return;
  }
  const float* in; u16* out; int K, N, n0, k0;
  if (blk < XBLK + QTBLK) {
    const int t = blk - XBLK;
    in = Wqkv; out = wqkvt; K = DIM; N = NQKV;
    n0 = (t % (NQKV / 32)) * 32; k0 = (t / (NQKV / 32)) * 32;
  } else {
    const int t = blk - XBLK - QTBLK;
    in = Wproj; out = wprojt; K = DIM; N = DIM;
    n0 = (t % (DIM / 32)) * 32; k0 = (t / (DIM / 32)) * 32;
  }
  const int tx = threadIdx.x & 31, ty = threadIdx.x >> 5;
  #pragma unroll
  for (int i = 0; i < 32; i += 8)
    tile[ty + i][tx] = f2bf(in[(size_t)(k0 + ty + i) * N + n0 + tx]);
  __syncthreads();
  #pragma unroll
  for (int i = 0; i < 32; i += 8)
    out[(size_t)(n0 + ty + i) * K + k0 + tx] = tile[tx][ty + i];
}

// ---------------- GEMM1: qkv = x * Wqkv^T + b, 128x128 tile, BK=64 ----------------
// R13 proven: counted-vmcnt frame (2 buffers, 8 gloads/batch, vmcnt(8) across
// barrier, 32 MFMA per barrier-pair, 2 blocks/CU) + [128][64] XOR chunk-swizzle
// layout (chunk ^= row&7 on global source and fragment reads; 3.7x lower
// per-read bank conflicts than split-half layout).
__global__ __launch_bounds__(256)
void gemm_qkv(const u16* __restrict__ A, const u16* __restrict__ Bt,
              const float* __restrict__ bias, u16* __restrict__ qkv) {
  __shared__ __align__(16) u16 smem[2 * 16384];   // 64 KB: 2 x (A[128][64] + B[128][64])
  const int tid = threadIdx.x;
  const int w = tid >> 6, lane = tid & 63;
  const int l15 = lane & 15, quad = lane >> 4;
  const int b_ = blockIdx.x;
  const int xcd = b_ & 7, j = b_ >> 3;
  const int m0 = ((j & 7) * 8 + xcd) * 128;   // 0..63 * 128
  const int n0 = (j >> 3) * 128;              // 0..17 * 128
  const int wm = (w >> 1) * 64, wn = (w & 1) * 64;

  f32x4 acc[4][4] = {};

  const int srow = tid >> 3;                  // 0..31
  const int schunk = (tid & 7) ^ (srow & 7);
  const u16* ga = A  + (size_t)(m0 + srow) * DIM + schunk * 8;
  const u16* gb = Bt + (size_t)(n0 + srow) * DIM + schunk * 8;
  const int ldst = tid * 8;

  auto qstage = [&](int c, int k0) {
    u16* base = smem + c * 16384;
    #pragma unroll
    for (int t = 0; t < 4; ++t) {
      gload16(ga + (size_t)t * 32 * DIM + k0, base + t * 2048 + ldst);
      gload16(gb + (size_t)t * 32 * DIM + k0, base + 8192 + t * 2048 + ldst);
    }
  };

  qstage(0, 0);   // batch 0 -> buf0

  #pragma unroll
  for (int it = 0; it < 12; ++it) {
    const int cur = it & 1;
    if (it < 11) qstage(cur ^ 1, (it + 1) * 64);   // batch it+1 -> buf^1
    if (it < 11) asm volatile("s_waitcnt vmcnt(8)" ::: "memory");
    else         asm volatile("s_waitcnt vmcnt(0)" ::: "memory");
    __builtin_amdgcn_s_barrier();

    const u16* lA = smem + cur * 16384;
    const u16* lB = lA + 8192;
    const int sx = l15 & 7;
    short8 af[4][2], bfr[4][2];
    #pragma unroll
    for (int kh = 0; kh < 2; ++kh) {
      #pragma unroll
      for (int mt = 0; mt < 4; ++mt)
        af[mt][kh] = *(const short8*)&lA[(wm + mt * 16 + l15) * 64 + (((kh * 4 + quad) ^ sx) * 8)];
      #pragma unroll
      for (int nt = 0; nt < 4; ++nt)
        bfr[nt][kh] = *(const short8*)&lB[(wn + nt * 16 + l15) * 64 + (((kh * 4 + quad) ^ sx) * 8)];
    }

    asm volatile("s_waitcnt lgkmcnt(0)" ::: "memory");
    __builtin_amdgcn_s_barrier();

    #pragma unroll
    for (int kh = 0; kh < 2; ++kh)
      #pragma unroll
      for (int mt = 0; mt < 4; ++mt)
        #pragma unroll
        for (int nt = 0; nt < 4; ++nt)
          acc[mt][nt] = __builtin_amdgcn_mfma_f32_16x16x32_bf16(af[mt][kh], bfr[nt][kh], acc[mt][nt], 0, 0, 0);
  }

  const int bb = m0 >> 10;
  const int tb0 = (m0 & 1023) + wm;
  const int nh = n0 + wn;
  const int part = nh / DIM, idx = nh - part * DIM;
  const int h = idx >> 6;

  float bnl[4];
  #pragma unroll
  for (int nt = 0; nt < 4; ++nt) bnl[nt] = bias[nh + nt * 16 + l15];

  if (part < 2) {
    u16* dstbase = qkv + part * PSZ + ((size_t)(bb * HEADS + h) * SEQ + tb0) * HD;
    const float qsc = (part == 0) ? SCQ : 1.0f;
    const int erow = lane >> 3, ec8 = (lane & 7) * 8;
    #pragma unroll
    for (int mt = 0; mt < 4; ++mt) {
      u16* ep = smem + w * (16 * EPAD) + (mt & 1) * (4 * 16 * EPAD);
      #pragma unroll
      for (int nt = 0; nt < 4; ++nt)
        #pragma unroll
        for (int r = 0; r < 4; ++r)
          ep[(quad * 4 + r) * EPAD + nt * 16 + l15] = f2bf((acc[mt][nt][r] + bnl[nt]) * qsc);
      #pragma unroll
      for (int j2 = 0; j2 < 2; ++j2) {
        const int trow = j2 * 8 + erow;
        short8 vrow = *(const short8*)&ep[trow * EPAD + ec8];
        *(short8*)(dstbase + (size_t)(mt * 16 + trow) * HD + ec8) = vrow;
      }
    }
  } else {
    u16* vrow0 = qkv + 2 * PSZ + (size_t)(bb * HEADS + h) * HD * SEQ;
    #pragma unroll
    for (int nt = 0; nt < 4; ++nt) {
      const int d = nt * 16 + l15;
      u16* trow = vrow0 + (size_t)d * SEQ + tb0 + quad * 4;
      #pragma unroll
      for (int mt = 0; mt < 4; ++mt) {
        short4v pv;
        pv.x = (short)f2bf(acc[mt][nt][0] + bnl[nt]);
        pv.y = (short)f2bf(acc[mt][nt][1] + bnl[nt]);
        pv.z = (short)f2bf(acc[mt][nt][2] + bnl[nt]);
        pv.w = (short)f2bf(acc[mt][nt][3] + bnl[nt]);
        *(short4v*)(trow + mt * 16) = pv;
      }
    }
  }
}

// ---------------- GEMM2: out = y * Wproj^T + b (fp32 out, 128x128, BK=64) ----------------
// R13-qkv frame transplanted (third application of the twice-validated pattern):
// counted vmcnt(8) across the barrier (replaces the drain-vmcnt(0) at every
// __syncthreads) + [128][64] XOR chunk-swizzle layout. Grid 384, 2 blocks/CU.
__global__ __launch_bounds__(256)
void gemm_proj(const u16* __restrict__ A, const u16* __restrict__ Bt,
               const float* __restrict__ bias, float* __restrict__ outF) {
  __shared__ __align__(16) u16 smem[2 * 16384];   // 64 KB: 2 x (A[128][64] + B[128][64])
  const int tid = threadIdx.x;
  const int w = tid >> 6, lane = tid & 63;
  const int l15 = lane & 15, quad = lane >> 4;
  const int b_ = blockIdx.x;
  const int xcd = b_ & 7, j = b_ >> 3;        // j 0..47
  const int m0 = ((j & 7) * 8 + xcd) * 128;   // 0..63 * 128
  const int n0 = (j >> 3) * 128;              // 0..5 * 128
  const int wm = (w >> 1) * 64, wn = (w & 1) * 64;

  f32x4 acc[4][4] = {};

  const int srow = tid >> 3;                  // 0..31
  const int schunk = (tid & 7) ^ (srow & 7);
  const u16* ga = A  + (size_t)(m0 + srow) * DIM + schunk * 8;
  const u16* gb = Bt + (size_t)(n0 + srow) * DIM + schunk * 8;
  const int ldst = tid * 8;

  auto pstage = [&](int c, int k0) {
    u16* base = smem + c * 16384;
    #pragma unroll
    for (int t = 0; t < 4; ++t) {
      gload16(ga + (size_t)t * 32 * DIM + k0, base + t * 2048 + ldst);
      gload16(gb + (size_t)t * 32 * DIM + k0, base + 8192 + t * 2048 + ldst);
    }
  };

  pstage(0, 0);

  #pragma unroll
  for (int it = 0; it < 12; ++it) {
    const int cur = it & 1;
    if (it < 11) pstage(cur ^ 1, (it + 1) * 64);
    if (it < 11) asm volatile("s_waitcnt vmcnt(8)" ::: "memory");
    else         asm volatile("s_waitcnt vmcnt(0)" ::: "memory");
    __builtin_amdgcn_s_barrier();

    const u16* lA = smem + cur * 16384;
    const u16* lB = lA + 8192;
    const int sx = l15 & 7;
    short8 af[4][2], bfr[4][2];
    #pragma unroll
    for (int kh = 0; kh < 2; ++kh) {
      #pragma unroll
      for (int mt = 0; mt < 4; ++mt)
        af[mt][kh] = *(const short8*)&lA[(wm + mt * 16 + l15) * 64 + (((kh * 4 + quad) ^ sx) * 8)];
      #pragma unroll
      for (int nt = 0; nt < 4; ++nt)
        bfr[nt][kh] = *(const short8*)&lB[(wn + nt * 16 + l15) * 64 + (((kh * 4 + quad) ^ sx) * 8)];
    }

    asm volatile("s_waitcnt lgkmcnt(0)" ::: "memory");
    __builtin_amdgcn_s_barrier();

    #pragma unroll
    for (int kh = 0; kh < 2; ++kh)
      #pragma unroll
      for (int mt = 0; mt < 4; ++mt)
        #pragma unroll
        for (int nt = 0; nt < 4; ++nt)
          acc[mt][nt] = __builtin_amdgcn_mfma_f32_16x16x32_bf16(af[mt][kh], bfr[nt][kh], acc[mt][nt], 0, 0, 0);
  }

  #pragma unroll
  for (int nt = 0; nt < 4; ++nt) {
    const int n = n0 + wn + nt * 16 + l15;
    const float bn = bias[n];
    #pragma unroll
    for (int mt = 0; mt < 4; ++mt)
      #pragma unroll
      for (int r = 0; r < 4; ++r) {
        const int m = m0 + wm + mt * 16 + quad * 4 + r;
        outF[(size_t)m * DIM + n] = acc[mt][nt][r] + bn;
      }
  }
}

// ---------------- flash attention: 8 waves = 4 row-groups x 2 key-halves ----------------
// Round-11 proven: gload_lds K/V staging, linear [64][64] dbuf tiles with XOR
// chunk-swizzle (chunk ^= row&7) on global source + fragment reads; counted
// vmcnt(2) across the barrier.
__global__ __launch_bounds__(512, 4)
void attn_k(const u16* __restrict__ qb, const u16* __restrict__ kb,
            const u16* __restrict__ vtb, u16* __restrict__ yb) {
  const int bh = blockIdx.x, qt = blockIdx.y;
  const int tid = threadIdx.x;
  const int w = tid >> 6, lane = tid & 63;
  const int l15 = lane & 15, quad = lane >> 4;
  const int rg = w & 3;          // row-group: 32 rows each
  const int kh = w >> 2;         // key-half: keys kh*32..kh*32+31
  const int nt0 = kh * 2;

  __shared__ __align__(16) u16 smem[26624];   // 53248 B
  u16* lPq = smem + 16384 + rg * 2304;
  u16* stg = smem + 17408 + rg * 2304;
  float* fo = (float*)smem;

  const u16* qrow = qb + ((size_t)bh * SEQ + qt * 128 + rg * 32 + l15) * HD;
  short8 aq[2][2];
  #pragma unroll
  for (int qg = 0; qg < 2; ++qg) {
    aq[qg][0] = *(const short8*)(qrow + (size_t)qg * 16 * HD + quad * 8);
    aq[qg][1] = *(const short8*)(qrow + (size_t)qg * 16 * HD + 32 + quad * 8);
  }

  f32x4 o[2][4] = {};
  f32x4 sum[2] = {};

  const u16* kcbase = kb + (size_t)bh * SEQ * HD;
  const u16* vbase  = vtb + (size_t)bh * HD * SEQ;

  const int srow = tid >> 3;
  const int schunk = (tid & 7) ^ (srow & 7);
  const u16* kgs = kcbase + (size_t)srow * HD + schunk * 8;   // + kc*4096
  const u16* vgs = vbase + (size_t)srow * SEQ + schunk * 8;   // + kc*64
  const int dst = tid * 8;

  auto stage = [&](int c, int kc) {
    gload16(kgs + kc * 4096, smem + c * 8192 + dst);
    gload16(vgs + kc * 64,   smem + c * 8192 + 4096 + dst);
  };

  short8 ones;
  #pragma unroll
  for (int i = 0; i < 8; ++i) ones[i] = (short)0x3f80;   // bf16 1.0

  stage(0, 0);

  for (int kc = 0; kc < 16; ++kc) {
    const int cur = kc & 1;
    if (kc < 15) stage(cur ^ 1, kc + 1);
    if (kc < 15) asm volatile("s_waitcnt vmcnt(2)" ::: "memory");
    else         asm volatile("s_waitcnt vmcnt(0)" ::: "memory");
    __builtin_amdgcn_s_barrier();

    const u16* lK = smem + cur * 8192;
    const u16* lV = lK + 4096;
    const int sx = l15 & 7;

    short8 akf[2][2];
    #pragma unroll
    for (int i = 0; i < 2; ++i) {
      const int key = (nt0 + i) * 16 + l15;
      akf[i][0] = *(const short8*)&lK[key * 64 + ((quad ^ sx) * 8)];
      akf[i][1] = *(const short8*)&lK[key * 64 + (((4 + quad) ^ sx) * 8)];
    }

    #pragma unroll
    for (int qg = 0; qg < 2; ++qg) {
      f32x4 s0 = {}, s1 = {};
      __builtin_amdgcn_s_setprio(1);
      s0 = __builtin_amdgcn_mfma_f32_16x16x32_bf16(akf[0][0], aq[qg][0], s0, 0, 0, 0);
      s0 = __builtin_amdgcn_mfma_f32_16x16x32_bf16(akf[0][1], aq[qg][1], s0, 0, 0, 0);
      s1 = __builtin_amdgcn_mfma_f32_16x16x32_bf16(akf[1][0], aq[qg][0], s1, 0, 0, 0);
      s1 = __builtin_amdgcn_mfma_f32_16x16x32_bf16(akf[1][1], aq[qg][1], s1, 0, 0, 0);
      __builtin_amdgcn_s_setprio(0);
      #pragma unroll
      for (int i = 0; i < 2; ++i) {
        const f32x4 s = i ? s1 : s0;
        float p0 = __builtin_amdgcn_exp2f(s[0]);
        float p1 = __builtin_amdgcn_exp2f(s[1]);
        float p2 = __builtin_amdgcn_exp2f(s[2]);
        float p3 = __builtin_amdgcn_exp2f(s[3]);
        int2v pkk;
        pkk.x = (int)__builtin_amdgcn_perm(__float_as_uint(p1), __float_as_uint(p0), 0x07060302u);
        pkk.y = (int)__builtin_amdgcn_perm(__float_as_uint(p3), __float_as_uint(p2), 0x07060302u);
        *(int2v*)&lPq[(qg * 16 + l15) * KP + (nt0 + i) * 16 + quad * 4] = pkk;
      }
    }

    short8 bv[4];
    #pragma unroll
    for (int ntd = 0; ntd < 4; ++ntd)
      bv[ntd] = *(const short8*)&lV[(ntd * 16 + l15) * 64 + (((kh * 4 + quad) ^ sx) * 8)];

    #pragma unroll
    for (int qg = 0; qg < 2; ++qg) {
      const short8 ap = *(const short8*)&lPq[(qg * 16 + l15) * KP + kh * 32 + quad * 8];
      __builtin_amdgcn_s_setprio(1);
      #pragma unroll
      for (int ntd = 0; ntd < 4; ++ntd)
        o[qg][ntd] = __builtin_amdgcn_mfma_f32_16x16x32_bf16(ap, bv[ntd], o[qg][ntd], 0, 0, 0);
      sum[qg] = __builtin_amdgcn_mfma_f32_16x16x32_bf16(ap, ones, sum[qg], 0, 0, 0);
      __builtin_amdgcn_s_setprio(0);
    }

    asm volatile("s_waitcnt lgkmcnt(0)" ::: "memory");
    __builtin_amdgcn_s_barrier();
  }

  if (kh == 1) {
    #pragma unroll
    for (int qg = 0; qg < 2; ++qg)
      #pragma unroll
      for (int r = 0; r < 4; ++r) {
        const int row = rg * 32 + qg * 16 + quad * 4 + r;
        #pragma unroll
        for (int ntd = 0; ntd < 4; ++ntd)
          fo[row * 68 + ntd * 16 + l15] = o[qg][ntd][r];
        if (l15 == 0) fo[row * 68 + 64] = sum[qg][r];
      }
  }
  __syncthreads();

  if (kh == 0) {
    const int b = bh / HEADS, h = bh % HEADS;
    #pragma unroll
    for (int qg = 0; qg < 2; ++qg)
      #pragma unroll
      for (int r = 0; r < 4; ++r) {
        const int lrow = qg * 16 + quad * 4 + r;
        const int row = rg * 32 + lrow;
        const float s = sum[qg][r] + fo[row * 68 + 64];
        const float inv = 1.0f / s;
        #pragma unroll
        for (int ntd = 0; ntd < 4; ++ntd) {
          const float v = (o[qg][ntd][r] + fo[row * 68 + ntd * 16 + l15]) * inv;
          stg[lrow * KP + ntd * 16 + l15] = f2bf(v);
        }
      }
    u16* dst2 = yb + ((size_t)b * SEQ + qt * 128 + rg * 32) * DIM + h * HD;
    const int erow = lane >> 3, ec8 = (lane & 7) * 8;
    #pragma unroll
    for (int j = 0; j < 4; ++j) {
      const int trow = j * 8 + erow;
      short8 vrow = *(const short8*)&stg[trow * KP + ec8];
      *(short8*)(dst2 + (size_t)trow * DIM + ec8) = vrow;
    }
  }
}

// ---------------- launcher ----------------
extern "C" void kernel_launch(void* const* d_in, const int* in_sizes, int n_in,
                              void* d_out, int out_size, void* d_ws, size_t ws_size,
                              hipStream_t stream) {
  const float* x     = (const float*)d_in[0];
  const float* Wqkv  = (const float*)d_in[1];
  const float* bqkv  = (const float*)d_in[2];
  const float* Wproj = (const float*)d_in[3];
  const float* bproj = (const float*)d_in[4];
  float* out = (float*)d_out;

  u16* xb     = (u16*)d_ws;                       // 8192*768
  u16* wqkvt  = xb + (size_t)MTOK * DIM;
  u16* wprojt = wqkvt + (size_t)NQKV * DIM;
  u16* qkv_b  = wprojt + (size_t)DIM * DIM;       // q,k: [t][d]; v-slot holds vt [d][t]
  u16* y_b    = qkv_b + 3 * PSZ;

  cvt_all_k<<<XBLK + QTBLK + (DIM / 32) * (DIM / 32), 256, 0, stream>>>(
      x, Wqkv, Wproj, xb, wqkvt, wprojt);

  gemm_qkv<<<1152, 256, 0, stream>>>(xb, wqkvt, bqkv, qkv_b);

  attn_k<<<dim3(BATCH * HEADS, SEQ / 128), 512, 0, stream>>>(
      qkv_b, qkv_b + PSZ, qkv_b + 2 * PSZ, y_b);

  gemm_proj<<<384, 256, 0, stream>>>(y_b, wprojt, bproj, out);
}

// Round 15
// 178.154 us; speedup vs baseline: 1.0145x; 1.0145x over previous
//
#include <hip/hip_runtime.h>

typedef unsigned short u16;
typedef __attribute__((ext_vector_type(8))) short short8;
typedef __attribute__((ext_vector_type(4))) short short4v;
typedef __attribute__((ext_vector_type(2))) int int2v;
typedef __attribute__((ext_vector_type(4))) float f32x4;

#define DIM   768
#define HEADS 12
#define HD    64
#define BATCH 8
#define SEQ   1024
#define MTOK  (BATCH*SEQ)   /* 8192 */
#define NQKV  (3*DIM)       /* 2304 */
#define KP    72            /* attn P-region row stride (144B = 9*16B, b128-aligned) */
#define EPAD  66            /* gemm epilogue stage stride */
#define PSZ   ((size_t)BATCH*HEADS*SEQ*HD)   /* one of q/k/v */
#define SCQ   0.1803368801f /* hd^-0.5 * log2(e), folded into stored q */

__device__ __forceinline__ u16 f2bf(float f) {
  unsigned x = __float_as_uint(f);
  x += 0x7fffu + ((x >> 16) & 1u);      // RNE
  return (u16)(x >> 16);
}

__device__ __forceinline__ void gload16(const u16* g, u16* l) {
  __builtin_amdgcn_global_load_lds(
      (const __attribute__((address_space(1))) unsigned int*)g,
      (__attribute__((address_space(3))) unsigned int*)l, 16, 0, 0);
}

// ---------------- fused conversions: x->bf16, Wqkv^T, Wproj^T ----------------
#define XBLK 6144            /* MTOK*DIM/4/256 */
#define QTBLK 1728           /* (NQKV/32)*(DIM/32) */
__global__ void cvt_all_k(const float* __restrict__ x,
                          const float* __restrict__ Wqkv,
                          const float* __restrict__ Wproj,
                          u16* __restrict__ xb, u16* __restrict__ wqkvt,
                          u16* __restrict__ wprojt) {
  __shared__ u16 tile[32][33];
  const int blk = blockIdx.x;
  if (blk < XBLK) {
    const int i = blk * 256 + threadIdx.x;
    float4 f = ((const float4*)x)[i];
    short4v o;
    o.x = (short)f2bf(f.x); o.y = (short)f2bf(f.y);
    o.z = (short)f2bf(f.z); o.w = (short)f2bf(f.w);
    ((short4v*)xb)[i] = o;
    return;
  }
  const float* in; u16* out; int K, N, n0, k0;
  if (blk < XBLK + QTBLK) {
    const int t = blk - XBLK;
    in = Wqkv; out = wqkvt; K = DIM; N = NQKV;
    n0 = (t % (NQKV / 32)) * 32; k0 = (t / (NQKV / 32)) * 32;
  } else {
    const int t = blk - XBLK - QTBLK;
    in = Wproj; out = wprojt; K = DIM; N = DIM;
    n0 = (t % (DIM / 32)) * 32; k0 = (t / (DIM / 32)) * 32;
  }
  const int tx = threadIdx.x & 31, ty = threadIdx.x >> 5;
  #pragma unroll
  for (int i = 0; i < 32; i += 8)
    tile[ty + i][tx] = f2bf(in[(size_t)(k0 + ty + i) * N + n0 + tx]);
  __syncthreads();
  #pragma unroll
  for (int i = 0; i < 32; i += 8)
    out[(size_t)(n0 + ty + i) * K + k0 + tx] = tile[tx][ty + i];
}

// ---------------- GEMM1: qkv = x * Wqkv^T + b, 128x128 tile, BK=64 ----------------
// R13 proven: counted-vmcnt frame (2 buffers, 8 gloads/batch, vmcnt(8) across
// barrier, 32 MFMA per barrier-pair, 2 blocks/CU) + [128][64] XOR chunk-swizzle
// layout (chunk ^= row&7 on global source and fragment reads).
__global__ __launch_bounds__(256)
void gemm_qkv(const u16* __restrict__ A, const u16* __restrict__ Bt,
              const float* __restrict__ bias, u16* __restrict__ qkv) {
  __shared__ __align__(16) u16 smem[2 * 16384];   // 64 KB: 2 x (A[128][64] + B[128][64])
  const int tid = threadIdx.x;
  const int w = tid >> 6, lane = tid & 63;
  const int l15 = lane & 15, quad = lane >> 4;
  const int b_ = blockIdx.x;
  const int xcd = b_ & 7, j = b_ >> 3;
  const int m0 = ((j & 7) * 8 + xcd) * 128;   // 0..63 * 128
  const int n0 = (j >> 3) * 128;              // 0..17 * 128
  const int wm = (w >> 1) * 64, wn = (w & 1) * 64;

  f32x4 acc[4][4] = {};

  const int srow = tid >> 3;                  // 0..31
  const int schunk = (tid & 7) ^ (srow & 7);
  const u16* ga = A  + (size_t)(m0 + srow) * DIM + schunk * 8;
  const u16* gb = Bt + (size_t)(n0 + srow) * DIM + schunk * 8;
  const int ldst = tid * 8;

  auto qstage = [&](int c, int k0) {
    u16* base = smem + c * 16384;
    #pragma unroll
    for (int t = 0; t < 4; ++t) {
      gload16(ga + (size_t)t * 32 * DIM + k0, base + t * 2048 + ldst);
      gload16(gb + (size_t)t * 32 * DIM + k0, base + 8192 + t * 2048 + ldst);
    }
  };

  qstage(0, 0);   // batch 0 -> buf0

  #pragma unroll
  for (int it = 0; it < 12; ++it) {
    const int cur = it & 1;
    if (it < 11) qstage(cur ^ 1, (it + 1) * 64);   // batch it+1 -> buf^1
    if (it < 11) asm volatile("s_waitcnt vmcnt(8)" ::: "memory");
    else         asm volatile("s_waitcnt vmcnt(0)" ::: "memory");
    __builtin_amdgcn_s_barrier();

    const u16* lA = smem + cur * 16384;
    const u16* lB = lA + 8192;
    const int sx = l15 & 7;
    short8 af[4][2], bfr[4][2];
    #pragma unroll
    for (int kh = 0; kh < 2; ++kh) {
      #pragma unroll
      for (int mt = 0; mt < 4; ++mt)
        af[mt][kh] = *(const short8*)&lA[(wm + mt * 16 + l15) * 64 + (((kh * 4 + quad) ^ sx) * 8)];
      #pragma unroll
      for (int nt = 0; nt < 4; ++nt)
        bfr[nt][kh] = *(const short8*)&lB[(wn + nt * 16 + l15) * 64 + (((kh * 4 + quad) ^ sx) * 8)];
    }

    asm volatile("s_waitcnt lgkmcnt(0)" ::: "memory");
    __builtin_amdgcn_s_barrier();

    #pragma unroll
    for (int kh = 0; kh < 2; ++kh)
      #pragma unroll
      for (int mt = 0; mt < 4; ++mt)
        #pragma unroll
        for (int nt = 0; nt < 4; ++nt)
          acc[mt][nt] = __builtin_amdgcn_mfma_f32_16x16x32_bf16(af[mt][kh], bfr[nt][kh], acc[mt][nt], 0, 0, 0);
  }

  const int bb = m0 >> 10;
  const int tb0 = (m0 & 1023) + wm;
  const int nh = n0 + wn;
  const int part = nh / DIM, idx = nh - part * DIM;
  const int h = idx >> 6;

  float bnl[4];
  #pragma unroll
  for (int nt = 0; nt < 4; ++nt) bnl[nt] = bias[nh + nt * 16 + l15];

  if (part < 2) {
    u16* dstbase = qkv + part * PSZ + ((size_t)(bb * HEADS + h) * SEQ + tb0) * HD;
    const float qsc = (part == 0) ? SCQ : 1.0f;
    const int erow = lane >> 3, ec8 = (lane & 7) * 8;
    #pragma unroll
    for (int mt = 0; mt < 4; ++mt) {
      u16* ep = smem + w * (16 * EPAD) + (mt & 1) * (4 * 16 * EPAD);
      #pragma unroll
      for (int nt = 0; nt < 4; ++nt)
        #pragma unroll
        for (int r = 0; r < 4; ++r)
          ep[(quad * 4 + r) * EPAD + nt * 16 + l15] = f2bf((acc[mt][nt][r] + bnl[nt]) * qsc);
      #pragma unroll
      for (int j2 = 0; j2 < 2; ++j2) {
        const int trow = j2 * 8 + erow;
        short8 vrow = *(const short8*)&ep[trow * EPAD + ec8];
        *(short8*)(dstbase + (size_t)(mt * 16 + trow) * HD + ec8) = vrow;
      }
    }
  } else {
    u16* vrow0 = qkv + 2 * PSZ + (size_t)(bb * HEADS + h) * HD * SEQ;
    #pragma unroll
    for (int nt = 0; nt < 4; ++nt) {
      const int d = nt * 16 + l15;
      u16* trow = vrow0 + (size_t)d * SEQ + tb0 + quad * 4;
      #pragma unroll
      for (int mt = 0; mt < 4; ++mt) {
        short4v pv;
        pv.x = (short)f2bf(acc[mt][nt][0] + bnl[nt]);
        pv.y = (short)f2bf(acc[mt][nt][1] + bnl[nt]);
        pv.z = (short)f2bf(acc[mt][nt][2] + bnl[nt]);
        pv.w = (short)f2bf(acc[mt][nt][3] + bnl[nt]);
        *(short4v*)(trow + mt * 16) = pv;
      }
    }
  }
}

// ---------------- GEMM2: out = y * Wproj^T + b (fp32 out, 128x128, BK=64) ----------------
// R14 proven: counted vmcnt(8) + [128][64] XOR chunk-swizzle layout. Grid 384.
__global__ __launch_bounds__(256)
void gemm_proj(const u16* __restrict__ A, const u16* __restrict__ Bt,
               const float* __restrict__ bias, float* __restrict__ outF) {
  __shared__ __align__(16) u16 smem[2 * 16384];   // 64 KB
  const int tid = threadIdx.x;
  const int w = tid >> 6, lane = tid & 63;
  const int l15 = lane & 15, quad = lane >> 4;
  const int b_ = blockIdx.x;
  const int xcd = b_ & 7, j = b_ >> 3;        // j 0..47
  const int m0 = ((j & 7) * 8 + xcd) * 128;   // 0..63 * 128
  const int n0 = (j >> 3) * 128;              // 0..5 * 128
  const int wm = (w >> 1) * 64, wn = (w & 1) * 64;

  f32x4 acc[4][4] = {};

  const int srow = tid >> 3;                  // 0..31
  const int schunk = (tid & 7) ^ (srow & 7);
  const u16* ga = A  + (size_t)(m0 + srow) * DIM + schunk * 8;
  const u16* gb = Bt + (size_t)(n0 + srow) * DIM + schunk * 8;
  const int ldst = tid * 8;

  auto pstage = [&](int c, int k0) {
    u16* base = smem + c * 16384;
    #pragma unroll
    for (int t = 0; t < 4; ++t) {
      gload16(ga + (size_t)t * 32 * DIM + k0, base + t * 2048 + ldst);
      gload16(gb + (size_t)t * 32 * DIM + k0, base + 8192 + t * 2048 + ldst);
    }
  };

  pstage(0, 0);

  #pragma unroll
  for (int it = 0; it < 12; ++it) {
    const int cur = it & 1;
    if (it < 11) pstage(cur ^ 1, (it + 1) * 64);
    if (it < 11) asm volatile("s_waitcnt vmcnt(8)" ::: "memory");
    else         asm volatile("s_waitcnt vmcnt(0)" ::: "memory");
    __builtin_amdgcn_s_barrier();

    const u16* lA = smem + cur * 16384;
    const u16* lB = lA + 8192;
    const int sx = l15 & 7;
    short8 af[4][2], bfr[4][2];
    #pragma unroll
    for (int kh = 0; kh < 2; ++kh) {
      #pragma unroll
      for (int mt = 0; mt < 4; ++mt)
        af[mt][kh] = *(const short8*)&lA[(wm + mt * 16 + l15) * 64 + (((kh * 4 + quad) ^ sx) * 8)];
      #pragma unroll
      for (int nt = 0; nt < 4; ++nt)
        bfr[nt][kh] = *(const short8*)&lB[(wn + nt * 16 + l15) * 64 + (((kh * 4 + quad) ^ sx) * 8)];
    }

    asm volatile("s_waitcnt lgkmcnt(0)" ::: "memory");
    __builtin_amdgcn_s_barrier();

    #pragma unroll
    for (int kh = 0; kh < 2; ++kh)
      #pragma unroll
      for (int mt = 0; mt < 4; ++mt)
        #pragma unroll
        for (int nt = 0; nt < 4; ++nt)
          acc[mt][nt] = __builtin_amdgcn_mfma_f32_16x16x32_bf16(af[mt][kh], bfr[nt][kh], acc[mt][nt], 0, 0, 0);
  }

  #pragma unroll
  for (int nt = 0; nt < 4; ++nt) {
    const int n = n0 + wn + nt * 16 + l15;
    const float bn = bias[n];
    #pragma unroll
    for (int mt = 0; mt < 4; ++mt)
      #pragma unroll
      for (int r = 0; r < 4; ++r) {
        const int m = m0 + wm + mt * 16 + quad * 4 + r;
        outF[(size_t)m * DIM + n] = acc[mt][nt][r] + bn;
      }
  }
}

// ---------------- flash attention: 8 waves, paired-tile pipeline ----------------
// R11 frame + halved barrier count: 4 tile-slots (2 pairs x dbuf), stage a PAIR
// (4 gloads) per iteration with counted vmcnt(4), then TWO back-to-back inner
// sub-steps on the two pre-staged slots (different slots -> no inner fence).
// 8 barrier-pairs instead of 16. lPq shrunk to [16][72]/rg by interleaving PV
// per-qg (P region is wave-private per (rg,kh) cols; same-wave DS ordering
// makes write->read safe, as in R11). LDS 74752B -> 2 blocks/CU.
__global__ __launch_bounds__(512, 4)
void attn_k(const u16* __restrict__ qb, const u16* __restrict__ kb,
            const u16* __restrict__ vtb, u16* __restrict__ yb) {
  const int bh = blockIdx.x, qt = blockIdx.y;
  const int tid = threadIdx.x;
  const int w = tid >> 6, lane = tid & 63;
  const int l15 = lane & 15, quad = lane >> 4;
  const int rg = w & 3;          // row-group: 32 rows each
  const int kh = w >> 2;         // key-half within a 64-key tile
  const int nt0 = kh * 2;

  __shared__ __align__(16) u16 smem[37376];   // 74752 B
  // main loop: slots 0..3 @ s*8192 u16 (K[64][64] @0, V[64][64] @4096 each)
  //            lPq @32768 + rg*1152  ([16][72] per rg, wave-private per (rg,kh))
  // epilogue aliases slot region: fo = f32[128][68] @0 (17408 u16),
  //                               stg @17408 + rg*2304
  u16* lPq = smem + 32768 + rg * 1152;
  u16* stg = smem + 17408 + rg * 2304;
  float* fo = (float*)smem;

  const u16* qrow = qb + ((size_t)bh * SEQ + qt * 128 + rg * 32 + l15) * HD;
  short8 aq[2][2];
  #pragma unroll
  for (int qg = 0; qg < 2; ++qg) {
    aq[qg][0] = *(const short8*)(qrow + (size_t)qg * 16 * HD + quad * 8);
    aq[qg][1] = *(const short8*)(qrow + (size_t)qg * 16 * HD + 32 + quad * 8);
  }

  f32x4 o[2][4] = {};
  f32x4 sum[2] = {};

  const u16* kcbase = kb + (size_t)bh * SEQ * HD;
  const u16* vbase  = vtb + (size_t)bh * HD * SEQ;

  const int srow = tid >> 3;
  const int schunk = (tid & 7) ^ (srow & 7);
  const u16* kgs = kcbase + (size_t)srow * HD + schunk * 8;   // + tile*4096
  const u16* vgs = vbase + (size_t)srow * SEQ + schunk * 8;   // + tile*64
  const int dst = tid * 8;

  // stage tiles 2*tp, 2*tp+1 into slots slotbase, slotbase+1
  auto stage_pair = [&](int slotbase, int tp) {
    gload16(kgs + (size_t)(2 * tp)     * 4096, smem + (slotbase)     * 8192 + dst);
    gload16(vgs + (size_t)(2 * tp)     * 64,   smem + (slotbase)     * 8192 + 4096 + dst);
    gload16(kgs + (size_t)(2 * tp + 1) * 4096, smem + (slotbase + 1) * 8192 + dst);
    gload16(vgs + (size_t)(2 * tp + 1) * 64,   smem + (slotbase + 1) * 8192 + 4096 + dst);
  };

  short8 ones;
  #pragma unroll
  for (int i = 0; i < 8; ++i) ones[i] = (short)0x3f80;   // bf16 1.0

  stage_pair(0, 0);

  for (int p = 0; p < 8; ++p) {
    const int sb = (p & 1) * 2;
    if (p < 7) stage_pair(sb ^ 2, p + 1);
    // wait ONLY pair p (4 loads); pair p+1's 4 stay in flight across the barrier
    if (p < 7) asm volatile("s_waitcnt vmcnt(4)" ::: "memory");
    else       asm volatile("s_waitcnt vmcnt(0)" ::: "memory");
    __builtin_amdgcn_s_barrier();

    #pragma unroll
    for (int s = 0; s < 2; ++s) {
      const u16* lK = smem + (sb + s) * 8192;
      const u16* lV = lK + 4096;
      const int sx = l15 & 7;

      short8 akf[2][2];
      #pragma unroll
      for (int i = 0; i < 2; ++i) {
        const int key = (nt0 + i) * 16 + l15;
        akf[i][0] = *(const short8*)&lK[key * 64 + ((quad ^ sx) * 8)];
        akf[i][1] = *(const short8*)&lK[key * 64 + (((4 + quad) ^ sx) * 8)];
      }
      short8 bv[4];
      #pragma unroll
      for (int ntd = 0; ntd < 4; ++ntd)
        bv[ntd] = *(const short8*)&lV[(ntd * 16 + l15) * 64 + (((kh * 4 + quad) ^ sx) * 8)];

      #pragma unroll
      for (int qg = 0; qg < 2; ++qg) {
        f32x4 s0 = {}, s1 = {};
        __builtin_amdgcn_s_setprio(1);
        s0 = __builtin_amdgcn_mfma_f32_16x16x32_bf16(akf[0][0], aq[qg][0], s0, 0, 0, 0);
        s0 = __builtin_amdgcn_mfma_f32_16x16x32_bf16(akf[0][1], aq[qg][1], s0, 0, 0, 0);
        s1 = __builtin_amdgcn_mfma_f32_16x16x32_bf16(akf[1][0], aq[qg][0], s1, 0, 0, 0);
        s1 = __builtin_amdgcn_mfma_f32_16x16x32_bf16(akf[1][1], aq[qg][1], s1, 0, 0, 0);
        __builtin_amdgcn_s_setprio(0);
        #pragma unroll
        for (int i = 0; i < 2; ++i) {
          const f32x4 sv = i ? s1 : s0;
          float p0 = __builtin_amdgcn_exp2f(sv[0]);
          float p1 = __builtin_amdgcn_exp2f(sv[1]);
          float p2 = __builtin_amdgcn_exp2f(sv[2]);
          float p3 = __builtin_amdgcn_exp2f(sv[3]);
          int2v pkk;
          pkk.x = (int)__builtin_amdgcn_perm(__float_as_uint(p1), __float_as_uint(p0), 0x07060302u);
          pkk.y = (int)__builtin_amdgcn_perm(__float_as_uint(p3), __float_as_uint(p2), 0x07060302u);
          *(int2v*)&lPq[l15 * KP + (nt0 + i) * 16 + quad * 4] = pkk;
        }
        const short8 ap = *(const short8*)&lPq[l15 * KP + kh * 32 + quad * 8];
        __builtin_amdgcn_s_setprio(1);
        #pragma unroll
        for (int ntd = 0; ntd < 4; ++ntd)
          o[qg][ntd] = __builtin_amdgcn_mfma_f32_16x16x32_bf16(ap, bv[ntd], o[qg][ntd], 0, 0, 0);
        sum[qg] = __builtin_amdgcn_mfma_f32_16x16x32_bf16(ap, ones, sum[qg], 0, 0, 0);
        __builtin_amdgcn_s_setprio(0);
      }
    }

    // WAR fence: all lanes' LDS reads of slots sb,sb+1 done before anyone can
    // issue the DMA that overwrites them (at iter p+1's stage_pair)
    asm volatile("s_waitcnt lgkmcnt(0)" ::: "memory");
    __builtin_amdgcn_s_barrier();
  }

  // ---- combine key-halves: kh=1 publishes partials, kh=0 finishes ----
  if (kh == 1) {
    #pragma unroll
    for (int qg = 0; qg < 2; ++qg)
      #pragma unroll
      for (int r = 0; r < 4; ++r) {
        const int row = rg * 32 + qg * 16 + quad * 4 + r;
        #pragma unroll
        for (int ntd = 0; ntd < 4; ++ntd)
          fo[row * 68 + ntd * 16 + l15] = o[qg][ntd][r];
        if (l15 == 0) fo[row * 68 + 64] = sum[qg][r];
      }
  }
  __syncthreads();

  if (kh == 0) {
    const int b = bh / HEADS, h = bh % HEADS;
    #pragma unroll
    for (int qg = 0; qg < 2; ++qg)
      #pragma unroll
      for (int r = 0; r < 4; ++r) {
        const int lrow = qg * 16 + quad * 4 + r;
        const int row = rg * 32 + lrow;
        const float s = sum[qg][r] + fo[row * 68 + 64];
        const float inv = 1.0f / s;
        #pragma unroll
        for (int ntd = 0; ntd < 4; ++ntd) {
          const float v = (o[qg][ntd][r] + fo[row * 68 + ntd * 16 + l15]) * inv;
          stg[lrow * KP + ntd * 16 + l15] = f2bf(v);
        }
      }
    u16* dst2 = yb + ((size_t)b * SEQ + qt * 128 + rg * 32) * DIM + h * HD;
    const int erow = lane >> 3, ec8 = (lane & 7) * 8;
    #pragma unroll
    for (int j = 0; j < 4; ++j) {
      const int trow = j * 8 + erow;
      short8 vrow = *(const short8*)&stg[trow * KP + ec8];
      *(short8*)(dst2 + (size_t)trow * DIM + ec8) = vrow;
    }
  }
}

// ---------------- launcher ----------------
extern "C" void kernel_launch(void* const* d_in, const int* in_sizes, int n_in,
                              void* d_out, int out_size, void* d_ws, size_t ws_size,
                              hipStream_t stream) {
  const float* x     = (const float*)d_in[0];
  const float* Wqkv  = (const float*)d_in[1];
  const float* bqkv  = (const float*)d_in[2];
  const float* Wproj = (const float*)d_in[3];
  const float* bproj = (const float*)d_in[4];
  float* out = (float*)d_out;

  u16* xb     = (u16*)d_ws;                       // 8192*768
  u16* wqkvt  = xb + (size_t)MTOK * DIM;
  u16* wprojt = wqkvt + (size_t)NQKV * DIM;
  u16* qkv_b  = wprojt + (size_t)DIM * DIM;       // q,k: [t][d]; v-slot holds vt [d][t]
  u16* y_b    = qkv_b + 3 * PSZ;

  cvt_all_k<<<XBLK + QTBLK + (DIM / 32) * (DIM / 32), 256, 0, stream>>>(
      x, Wqkv, Wproj, xb, wqkvt, wprojt);

  gemm_qkv<<<1152, 256, 0, stream>>>(xb, wqkvt, bqkv, qkv_b);

  attn_k<<<dim3(BATCH * HEADS, SEQ / 128), 512, 0, stream>>>(
      qkv_b, qkv_b + PSZ, qkv_b + 2 * PSZ, y_b);

  gemm_proj<<<384, 256, 0, stream>>>(y_b, wprojt, bproj, out);
}